// Round 3
// baseline (136.866 us; speedup 1.0000x reference)
//
#include <hip/hip_runtime.h>
#include <hip/hip_bf16.h>
#include <math.h>

typedef __attribute__((ext_vector_type(8))) short      bf16x8;
typedef __attribute__((ext_vector_type(8))) unsigned short u16x8;
typedef __attribute__((ext_vector_type(4))) unsigned short u16x4;
typedef __attribute__((ext_vector_type(4))) float       f32x4;

#define BB 8
#define CC 64
#define HH 128
#define WW 128
#define EE 16
#define DTXT 512
#define HWSZ 16384
#define NPAIR 16
#define WCHUNKS 4608           // 2chunk * 9k * 4slot * 64co 16B chunks per pair

static __device__ __forceinline__ unsigned short f2bf(float f) {
  unsigned u = __float_as_uint(f);
  unsigned r = (u + 0x7FFFu + ((u >> 16) & 1u)) >> 16;  // RNE
  return (unsigned short)r;
}
static __device__ __forceinline__ float bf2f(unsigned short s) {
  return __uint_as_float(((unsigned)s) << 16);
}

// ---------------------------------------------------------------- gate
__global__ __launch_bounds__(256) void gate_kernel(const float* __restrict__ pooled,
                                                   const float* __restrict__ text,
                                                   const float* __restrict__ Wx,
                                                   const float* __restrict__ Wt,
                                                   int* __restrict__ eidx,
                                                   float* __restrict__ gval,
                                                   float* __restrict__ aux_out) {
  __shared__ float logits[BB][EE];
  __shared__ float gates[BB][EE];
  __shared__ float imp[EE];
  const int t = threadIdx.x;
  if (t < BB * EE) {
    const int b = t >> 4, e = t & 15;
    float s = 0.f;
    for (int c = 0; c < CC; ++c) s += pooled[b * CC + c] * Wx[c * EE + e];
    for (int d = 0; d < DTXT; ++d) s += text[b * DTXT + d] * Wt[d * EE + e];
    logits[b][e] = s;
    gates[b][e] = 0.f;
  }
  __syncthreads();
  if (t < BB) {
    const int b = t;
    float v0 = -1e30f; int i0 = 0;
    for (int e = 0; e < EE; ++e) {
      float v = logits[b][e];
      if (v > v0) { v0 = v; i0 = e; }
    }
    float v1 = -1e30f; int i1 = 0;
    for (int e = 0; e < EE; ++e) {
      if (e == i0) continue;
      float v = logits[b][e];
      if (v > v1) { v1 = v; i1 = e; }
    }
    const float ex = expf(v1 - v0);
    const float g0 = 1.f / (1.f + ex);
    const float g1 = ex / (1.f + ex);
    gates[b][i0] = g0;
    gates[b][i1] = g1;
    eidx[2 * b] = i0;      gval[2 * b] = g0;
    eidx[2 * b + 1] = i1;  gval[2 * b + 1] = g1;
  }
  __syncthreads();
  if (t < EE) {
    float s = 0.f;
    for (int b = 0; b < BB; ++b) s += gates[b][t];
    imp[t] = s;
  }
  __syncthreads();
  if (t == 0) {
    float m = 0.f;
    for (int e = 0; e < EE; ++e) m += imp[e];
    m *= (1.f / EE);
    float v = 0.f;
    for (int e = 0; e < EE; ++e) { float d = imp[e] - m; v += d * d; }
    v *= (1.f / EE);
    aux_out[0] = v / (m * m + 1e-10f);
  }
}

// ---------------------------------------------------------------- xtprep (+fused pool)
// x[b][ci][px] fp32 -> xT[b][px][ci] bf16, and pooled[b][ci] += colsum/HW.
__global__ __launch_bounds__(256) void xtprep_kernel(const float* __restrict__ x,
                                                     unsigned short* __restrict__ xT,
                                                     float* __restrict__ pooled) {
  __shared__ unsigned short lt[256 * 70];
  const int b = blockIdx.y, p0 = blockIdx.x * 256;
  const int t = threadIdx.x;
  const float* xb = x + (size_t)b * CC * HWSZ + p0;
#pragma unroll 8
  for (int ci = 0; ci < CC; ++ci)
    lt[t * 70 + ci] = f2bf(xb[(size_t)ci * HWSZ + t]);
  __syncthreads();
  unsigned short* dstb = xT + ((size_t)b * HWSZ + p0) * CC;
#pragma unroll
  for (int it = 0; it < 8; ++it) {
    const int j = it * 256 + t;
    const int px = j >> 3, s = j & 7;
    u16x8 v;
#pragma unroll
    for (int i = 0; i < 8; ++i) v[i] = lt[px * 70 + s * 8 + i];
    *(u16x8*)(dstb + (size_t)j * 8) = v;
  }
  // fused pool: column sums from the transpose tile (bf16-rounded; error ~3e-5)
  const int ci = t & 63, q = t >> 6;
  float s = 0.f;
#pragma unroll 16
  for (int px = q * 64; px < q * 64 + 64; ++px) s += bf2f(lt[px * 70 + ci]);
  atomicAdd(&pooled[b * CC + ci], s * (1.f / (float)HWSZ));
}

// ---------------------------------------------------------------- wprep
// wp[pair][chunk2][k9][slot4][co64][8ci] bf16; gate folded into wp2.
__global__ __launch_bounds__(256) void wprep_kernel(const float* __restrict__ w1,
                                                    const float* __restrict__ w2,
                                                    const int* __restrict__ eidx,
                                                    const float* __restrict__ gval,
                                                    unsigned short* __restrict__ wp1,
                                                    unsigned short* __restrict__ wp2) {
  const int p = blockIdx.x;
  const int conv = blockIdx.y;
  const int e = eidx[p];
  const float g = conv ? gval[p] : 1.0f;
  const float* wsrc = (conv ? w2 : w1) + (size_t)e * CC * CC * 9;
  unsigned short* dst = (conv ? wp2 : wp1) + (size_t)p * WCHUNKS * 8;
  for (int c16 = threadIdx.x; c16 < WCHUNKS; c16 += 256) {
    const int co = c16 & 63;
    const int rest = c16 >> 6;
    const int s = rest & 3;
    const int ck = rest >> 2;
    const int k = ck % 9, chunk = ck / 9;
    const int ci0 = chunk * 32 + s * 8;
    u16x8 v;
#pragma unroll
    for (int i = 0; i < 8; ++i)
      v[i] = f2bf(g * wsrc[((size_t)co * CC + ci0 + i) * 9 + k]);
    *(u16x8*)(dst + (size_t)c16 * 8) = v;
  }
}

// ------------------------------------------------- conv core helpers
// stage x/h halo tile (18 x HCV px, 8 ci-chunks) into XOR-swizzled LDS
template <int HCV>
static __device__ __forceinline__ void stage_x(const u16x8* __restrict__ src,
                                               u16x8* xt, int ty0, int tx0, int t) {
  const int chunks = 18 * HCV * 8;
#pragma unroll
  for (int i = 0; i < (chunks + 511) / 512; ++i) {
    const int idx = i * 512 + t;
    if (idx < chunks) {
      const int ph = idx >> 3, s = idx & 7;
      const int yy = ph / HCV, xx = ph - yy * HCV;
      const int gy = ty0 - 1 + yy, gx = tx0 - 1 + xx;
      u16x8 v = (u16x8){0, 0, 0, 0, 0, 0, 0, 0};
      if ((unsigned)gy < (unsigned)HH && (unsigned)gx < (unsigned)WW)
        v = src[(gy * WW + gx) * 8 + s];
      xt[ph * 8 + (s ^ (ph & 7))] = v;
    }
  }
}

// A fragments straight from global (L2-hot), B from swizzled LDS.
template <int HCV, int NFC>
static __device__ __forceinline__ void conv_body(const u16x8* xt,
                                                 const u16x8* __restrict__ wg,
                                                 int lane, int w,
                                                 f32x4 acc[2][NFC][4]) {
  const int ks = lane >> 4;      // k-slot 0..3
  const int ln = lane & 15;
#pragma unroll
  for (int chunk = 0; chunk < 2; ++chunk) {
#pragma unroll
    for (int kk = 0; kk < 9; ++kk) {
      const int dy = kk / 3, dx = kk % 3;
      bf16x8 a[4];
#pragma unroll
      for (int mf = 0; mf < 4; ++mf)
        a[mf] = __builtin_bit_cast(bf16x8,
                  wg[((chunk * 9 + kk) * 4 + ks) * 64 + mf * 16 + ln]);
#pragma unroll
      for (int nfr = 0; nfr < 2; ++nfr)
#pragma unroll
        for (int nfc = 0; nfc < NFC; ++nfc) {
          const int row = 2 * w + nfr + dy;
          const int col = nfc * 16 + ln + dx;
          const int ph = row * HCV + col;
          const bf16x8 bfr = __builtin_bit_cast(bf16x8,
                    xt[ph * 8 + ((chunk * 4 + ks) ^ (ph & 7))]);
#pragma unroll
          for (int mf = 0; mf < 4; ++mf)
            acc[nfr][nfc][mf] = __builtin_amdgcn_mfma_f32_16x16x32_bf16(
                a[mf], bfr, acc[nfr][nfc][mf], 0, 0, 0);
        }
    }
  }
}

// ---------------------------------------------------------------- conv1
// grid (32 tiles 16x32, 16 pairs), 512 thr, 2 blocks/CU.
__global__ __launch_bounds__(512, 4) void conv1_kernel(const u16x8* __restrict__ xT,
                                                       const u16x8* __restrict__ wp1,
                                                       const float* __restrict__ b1,
                                                       const int* __restrict__ eidx,
                                                       unsigned short* __restrict__ h) {
  __shared__ u16x8 xt[18 * 34 * 8];
  const int t = threadIdx.x, lane = t & 63, w = t >> 6;
  const int tile = blockIdx.x, p = blockIdx.y;
  const int b = p >> 1, e = eidx[p];
  const int ty0 = (tile >> 2) * 16, tx0 = (tile & 3) * 32;

  f32x4 acc[2][2][4];
#pragma unroll
  for (int i = 0; i < 2; ++i)
#pragma unroll
    for (int j = 0; j < 2; ++j)
#pragma unroll
      for (int k = 0; k < 4; ++k) acc[i][j][k] = (f32x4){0.f, 0.f, 0.f, 0.f};

  stage_x<34>(xT + (size_t)b * HWSZ * 8, xt, ty0, tx0, t);
  __syncthreads();
  conv_body<34, 2>(xt, wp1 + (size_t)p * WCHUNKS, lane, w, acc);

  const int co_s = (lane >> 4) * 4;
  const int ln = lane & 15;
#pragma unroll
  for (int mf = 0; mf < 4; ++mf) {
    const float4 bv = *(const float4*)(b1 + e * CC + mf * 16 + co_s);
#pragma unroll
    for (int nfr = 0; nfr < 2; ++nfr)
#pragma unroll
      for (int nfc = 0; nfc < 2; ++nfc) {
        const int row = 2 * w + nfr, col = nfc * 16 + ln;
        const int gpx = (ty0 + row) * WW + tx0 + col;
        f32x4 v = acc[nfr][nfc][mf];
        float r0 = v.x + bv.x, r1 = v.y + bv.y, r2 = v.z + bv.z, r3 = v.w + bv.w;
        r0 = 0.5f * r0 * (1.f + erff(r0 * 0.70710678118654752f));
        r1 = 0.5f * r1 * (1.f + erff(r1 * 0.70710678118654752f));
        r2 = 0.5f * r2 * (1.f + erff(r2 * 0.70710678118654752f));
        r3 = 0.5f * r3 * (1.f + erff(r3 * 0.70710678118654752f));
        u16x4 pk = {f2bf(r0), f2bf(r1), f2bf(r2), f2bf(r3)};
        *(u16x4*)(h + ((size_t)p * HWSZ + gpx) * CC + mf * 16 + co_s) = pk;
      }
  }
}

// ---------------------------------------------------------------- conv2
// grid (64 tiles 16x16, 8 batch), 512 thr, 2 blocks/CU. Loops both slots.
__global__ __launch_bounds__(512, 4) void conv2_kernel(const u16x8* __restrict__ h,
                                                       const u16x8* __restrict__ wp2,
                                                       const float* __restrict__ b2,
                                                       const int* __restrict__ eidx,
                                                       const float* __restrict__ gval,
                                                       float* __restrict__ out) {
  __shared__ u16x8 xt[18 * 18 * 8];
  const int t = threadIdx.x, lane = t & 63, w = t >> 6;
  const int tile = blockIdx.x, b = blockIdx.y;
  const int ty0 = (tile >> 3) * 16, tx0 = (tile & 7) * 16;

  f32x4 acc[2][1][4];
#pragma unroll
  for (int i = 0; i < 2; ++i)
#pragma unroll
    for (int k = 0; k < 4; ++k) acc[i][0][k] = (f32x4){0.f, 0.f, 0.f, 0.f};

#pragma unroll
  for (int slot = 0; slot < 2; ++slot) {
    const int p = 2 * b + slot;
    if (slot) __syncthreads();
    stage_x<18>(h + (size_t)p * HWSZ * 8, xt, ty0, tx0, t);
    __syncthreads();
    conv_body<18, 1>(xt, wp2 + (size_t)p * WCHUNKS, lane, w, acc);
  }

  const int e0 = eidx[2 * b], e1 = eidx[2 * b + 1];
  const float g0 = gval[2 * b], g1 = gval[2 * b + 1];
  const int co_s = (lane >> 4) * 4;
  const int ln = lane & 15;
#pragma unroll
  for (int mf = 0; mf < 4; ++mf) {
    const float4 ba = *(const float4*)(b2 + e0 * CC + mf * 16 + co_s);
    const float4 bb = *(const float4*)(b2 + e1 * CC + mf * 16 + co_s);
    const float bx = g0 * ba.x + g1 * bb.x;
    const float by = g0 * ba.y + g1 * bb.y;
    const float bz = g0 * ba.z + g1 * bb.z;
    const float bw = g0 * ba.w + g1 * bb.w;
#pragma unroll
    for (int nfr = 0; nfr < 2; ++nfr) {
      const int row = 2 * w + nfr, col = ln;
      const int gpx = (ty0 + row) * WW + tx0 + col;
      f32x4 v = acc[nfr][0][mf];
      float* ob = out + (size_t)(b * CC + mf * 16 + co_s) * HWSZ + gpx;
      ob[0 * HWSZ] = v.x + bx;
      ob[1 * HWSZ] = v.y + by;
      ob[2 * HWSZ] = v.z + bz;
      ob[3 * HWSZ] = v.w + bw;
    }
  }
}

// ---------------------------------------------------------------- launch
extern "C" void kernel_launch(void* const* d_in, const int* in_sizes, int n_in,
                              void* d_out, int out_size, void* d_ws, size_t ws_size,
                              hipStream_t stream) {
  const float* x   = (const float*)d_in[0];
  const float* txt = (const float*)d_in[1];
  const float* Wx  = (const float*)d_in[2];
  const float* Wt  = (const float*)d_in[3];
  const float* w1  = (const float*)d_in[4];
  const float* b1  = (const float*)d_in[5];
  const float* w2  = (const float*)d_in[6];
  const float* b2  = (const float*)d_in[7];
  float* out = (float*)d_out;

  char* ws = (char*)d_ws;
  float* pooled = (float*)ws;                      // 2048 B
  int*   eidx   = (int*)(ws + 2048);               // 64 B
  float* gval   = (float*)(ws + 2112);             // 64 B
  unsigned short* wp1 = (unsigned short*)(ws + 4096);        // 1,179,648 B
  unsigned short* wp2 = (unsigned short*)(ws + 1183744);     // 1,179,648 B
  unsigned short* xT  = (unsigned short*)(ws + 2363392);     // 16,777,216 B
  unsigned short* h   = (unsigned short*)(ws + 19140608);    // 33,554,432 B

  hipMemsetAsync(pooled, 0, BB * CC * sizeof(float), stream);
  xtprep_kernel<<<dim3(64, 8), 256, 0, stream>>>(x, xT, pooled);
  gate_kernel<<<1, 256, 0, stream>>>(pooled, txt, Wx, Wt, eidx, gval,
                                     out + (out_size - 1));
  wprep_kernel<<<dim3(16, 2), 256, 0, stream>>>(w1, w2, eidx, gval, wp1, wp2);
  conv1_kernel<<<dim3(32, 16), 512, 0, stream>>>((const u16x8*)xT, (const u16x8*)wp1,
                                                 b1, eidx, (unsigned short*)h);
  conv2_kernel<<<dim3(64, 8), 512, 0, stream>>>((const u16x8*)h, (const u16x8*)wp2,
                                                b2, eidx, gval, out);
}

// Round 4
// 129.948 us; speedup vs baseline: 1.0532x; 1.0532x over previous
//
#include <hip/hip_runtime.h>
#include <hip/hip_bf16.h>
#include <math.h>

typedef __attribute__((ext_vector_type(8))) short      bf16x8;
typedef __attribute__((ext_vector_type(8))) unsigned short u16x8;
typedef __attribute__((ext_vector_type(4))) unsigned short u16x4;
typedef __attribute__((ext_vector_type(4))) float       f32x4;

#define BB 8
#define CC 64
#define HH 128
#define WW 128
#define EE 16
#define DTXT 512
#define HWSZ 16384
#define WCHUNKS 4608      // per pair: 2half * 9k * 4slot * 64co 16B chunks
#define WHALF 2304        // one 32-ci half
#define HLO 18            // 16x16 tile + halo
#define HPX2 324          // 18*18
#define XCH (HPX2 * 8)    // 2592 16B chunks

static __device__ __forceinline__ unsigned short f2bf(float f) {
  unsigned u = __float_as_uint(f);
  unsigned r = (u + 0x7FFFu + ((u >> 16) & 1u)) >> 16;  // RNE
  return (unsigned short)r;
}
static __device__ __forceinline__ float bf2f(unsigned short s) {
  return __uint_as_float(((unsigned)s) << 16);
}

// ---------------------------------------------------------------- gate
__global__ __launch_bounds__(256) void gate_kernel(const float* __restrict__ pooled,
                                                   const float* __restrict__ text,
                                                   const float* __restrict__ Wx,
                                                   const float* __restrict__ Wt,
                                                   int* __restrict__ eidx,
                                                   float* __restrict__ gval,
                                                   float* __restrict__ aux_out) {
  __shared__ float logits[BB][EE];
  __shared__ float gates[BB][EE];
  __shared__ float imp[EE];
  const int t = threadIdx.x;
  if (t < BB * EE) {
    const int b = t >> 4, e = t & 15;
    float s = 0.f;
    for (int c = 0; c < CC; ++c) s += pooled[b * CC + c] * Wx[c * EE + e];
    for (int d = 0; d < DTXT; ++d) s += text[b * DTXT + d] * Wt[d * EE + e];
    logits[b][e] = s;
    gates[b][e] = 0.f;
  }
  __syncthreads();
  if (t < BB) {
    const int b = t;
    float v0 = -1e30f; int i0 = 0;
    for (int e = 0; e < EE; ++e) {
      float v = logits[b][e];
      if (v > v0) { v0 = v; i0 = e; }
    }
    float v1 = -1e30f; int i1 = 0;
    for (int e = 0; e < EE; ++e) {
      if (e == i0) continue;
      float v = logits[b][e];
      if (v > v1) { v1 = v; i1 = e; }
    }
    const float ex = expf(v1 - v0);
    const float g0 = 1.f / (1.f + ex);
    const float g1 = ex / (1.f + ex);
    gates[b][i0] = g0;
    gates[b][i1] = g1;
    eidx[2 * b] = i0;      gval[2 * b] = g0;
    eidx[2 * b + 1] = i1;  gval[2 * b + 1] = g1;
  }
  __syncthreads();
  if (t < EE) {
    float s = 0.f;
    for (int b = 0; b < BB; ++b) s += gates[b][t];
    imp[t] = s;
  }
  __syncthreads();
  if (t == 0) {
    float m = 0.f;
    for (int e = 0; e < EE; ++e) m += imp[e];
    m *= (1.f / EE);
    float v = 0.f;
    for (int e = 0; e < EE; ++e) { float d = imp[e] - m; v += d * d; }
    v *= (1.f / EE);
    aux_out[0] = v / (m * m + 1e-10f);
  }
}

// ---------------------------------------------------------------- xtprep (+fused pool)
__global__ __launch_bounds__(256) void xtprep_kernel(const float* __restrict__ x,
                                                     unsigned short* __restrict__ xT,
                                                     float* __restrict__ pooled) {
  __shared__ unsigned short lt[256 * 70];
  const int b = blockIdx.y, p0 = blockIdx.x * 256;
  const int t = threadIdx.x;
  const float* xb = x + (size_t)b * CC * HWSZ + p0;
#pragma unroll 8
  for (int ci = 0; ci < CC; ++ci)
    lt[t * 70 + ci] = f2bf(xb[(size_t)ci * HWSZ + t]);
  __syncthreads();
  unsigned short* dstb = xT + ((size_t)b * HWSZ + p0) * CC;
#pragma unroll
  for (int it = 0; it < 8; ++it) {
    const int j = it * 256 + t;
    const int px = j >> 3, s = j & 7;
    u16x8 v;
#pragma unroll
    for (int i = 0; i < 8; ++i) v[i] = lt[px * 70 + s * 8 + i];
    *(u16x8*)(dstb + (size_t)j * 8) = v;
  }
  const int ci = t & 63, q = t >> 6;
  float s = 0.f;
#pragma unroll 16
  for (int px = q * 64; px < q * 64 + 64; ++px) s += bf2f(lt[px * 70 + ci]);
  atomicAdd(&pooled[b * CC + ci], s * (1.f / (float)HWSZ));
}

// ---------------------------------------------------------------- wprep
// wp[pair][half2][k9][slot4][co64][8ci] bf16; gate folded into wp2.
__global__ __launch_bounds__(256) void wprep_kernel(const float* __restrict__ w1,
                                                    const float* __restrict__ w2,
                                                    const int* __restrict__ eidx,
                                                    const float* __restrict__ gval,
                                                    unsigned short* __restrict__ wp1,
                                                    unsigned short* __restrict__ wp2) {
  const int p = blockIdx.x;
  const int conv = blockIdx.y;
  const int e = eidx[p];
  const float g = conv ? gval[p] : 1.0f;
  const float* wsrc = (conv ? w2 : w1) + (size_t)e * CC * CC * 9;
  unsigned short* dst = (conv ? wp2 : wp1) + (size_t)p * WCHUNKS * 8;
  for (int c16 = threadIdx.x; c16 < WCHUNKS; c16 += 256) {
    const int co = c16 & 63;
    const int rest = c16 >> 6;
    const int s = rest & 3;
    const int ck = rest >> 2;
    const int k = ck % 9, half = ck / 9;
    const int ci0 = half * 32 + s * 8;
    u16x8 v;
#pragma unroll
    for (int i = 0; i < 8; ++i)
      v[i] = f2bf(g * wsrc[((size_t)co * CC + ci0 + i) * 9 + k]);
    *(u16x8*)(dst + (size_t)c16 * 8) = v;
  }
}

// ------------------------------------------------- conv core helpers
static __device__ __forceinline__ void stage_xt(const u16x8* __restrict__ src,
                                                u16x8* xt, int ty0, int tx0, int t) {
#pragma unroll
  for (int i = 0; i < 6; ++i) {
    const int idx = i * 512 + t;
    if (idx < XCH) {
      const int ph = idx >> 3, s = idx & 7;
      const int yy = ph / HLO, xx = ph - yy * HLO;
      const int gy = ty0 - 1 + yy, gx = tx0 - 1 + xx;
      u16x8 v = (u16x8){0, 0, 0, 0, 0, 0, 0, 0};
      if ((unsigned)gy < (unsigned)HH && (unsigned)gx < (unsigned)WW)
        v = src[(gy * WW + gx) * 8 + s];
      xt[ph * 8 + (s ^ (ph & 7))] = v;
    }
  }
}

static __device__ __forceinline__ void stage_wt(u16x8* wt,
                                                const u16x8* __restrict__ wsrc, int t) {
#pragma unroll
  for (int i = 0; i < 5; ++i) {
    const int idx = i * 512 + t;
    if (idx < WHALF) wt[idx] = wsrc[idx];
  }
}

static __device__ __forceinline__ void half_body(const u16x8* xt, const u16x8* wt,
                                                 int half, int lane, int w,
                                                 f32x4 acc[2][4]) {
  const int ks = lane >> 4, ln = lane & 15;
#pragma unroll
  for (int kk = 0; kk < 9; ++kk) {
    const int dy = kk / 3, dx = kk % 3;
    bf16x8 a[4];
#pragma unroll
    for (int mf = 0; mf < 4; ++mf)
      a[mf] = __builtin_bit_cast(bf16x8, wt[(kk * 4 + ks) * 64 + mf * 16 + ln]);
#pragma unroll
    for (int nfr = 0; nfr < 2; ++nfr) {
      const int row = 2 * w + nfr + dy;
      const int col = ln + dx;
      const int ph = row * HLO + col;
      const bf16x8 bfr = __builtin_bit_cast(bf16x8,
                xt[ph * 8 + ((half * 4 + ks) ^ (ph & 7))]);
#pragma unroll
      for (int mf = 0; mf < 4; ++mf)
        acc[nfr][mf] = __builtin_amdgcn_mfma_f32_16x16x32_bf16(a[mf], bfr,
                                                               acc[nfr][mf], 0, 0, 0);
    }
  }
}

// ---------------------------------------------------------------- conv1
// grid (64 tiles 16x16, 16 pairs), 512 thr, 2 blocks/CU.
__global__ __launch_bounds__(512, 4) void conv1_kernel(const u16x8* __restrict__ xT,
                                                       const u16x8* __restrict__ wp1,
                                                       const float* __restrict__ b1,
                                                       const int* __restrict__ eidx,
                                                       unsigned short* __restrict__ h) {
  __shared__ u16x8 xt[XCH];
  __shared__ u16x8 wt[WHALF];
  const int t = threadIdx.x, lane = t & 63, w = t >> 6;
  const int tile = blockIdx.x, p = blockIdx.y;
  const int b = p >> 1, e = eidx[p];
  const int ty0 = (tile >> 3) * 16, tx0 = (tile & 7) * 16;

  f32x4 acc[2][4];
#pragma unroll
  for (int i = 0; i < 2; ++i)
#pragma unroll
    for (int j = 0; j < 4; ++j) acc[i][j] = (f32x4){0.f, 0.f, 0.f, 0.f};

  stage_xt(xT + (size_t)b * HWSZ * 8, xt, ty0, tx0, t);
  stage_wt(wt, wp1 + (size_t)p * WCHUNKS, t);
  __syncthreads();
  half_body(xt, wt, 0, lane, w, acc);
  __syncthreads();
  stage_wt(wt, wp1 + (size_t)p * WCHUNKS + WHALF, t);
  __syncthreads();
  half_body(xt, wt, 1, lane, w, acc);
  __syncthreads();   // xt readers done; reuse xt for the store bounce

  // epilogue: bias + exact GELU -> swizzled LDS bounce
  unsigned short* lt = (unsigned short*)xt;
  const int co_s = (lane >> 4) * 4;
  const int ln = lane & 15;
#pragma unroll
  for (int mf = 0; mf < 4; ++mf) {
    const float4 bv = *(const float4*)(b1 + e * CC + mf * 16 + co_s);
    const int s = mf * 2 + (co_s >> 3);
    const int off = co_s & 7;
#pragma unroll
    for (int nfr = 0; nfr < 2; ++nfr) {
      const int pxl = (2 * w + nfr) * 16 + ln;
      f32x4 v = acc[nfr][mf];
      float r0 = v.x + bv.x, r1 = v.y + bv.y, r2 = v.z + bv.z, r3 = v.w + bv.w;
      r0 = 0.5f * r0 * (1.f + erff(r0 * 0.70710678118654752f));
      r1 = 0.5f * r1 * (1.f + erff(r1 * 0.70710678118654752f));
      r2 = 0.5f * r2 * (1.f + erff(r2 * 0.70710678118654752f));
      r3 = 0.5f * r3 * (1.f + erff(r3 * 0.70710678118654752f));
      u16x4 pk = {f2bf(r0), f2bf(r1), f2bf(r2), f2bf(r3)};
      *(u16x4*)(lt + (pxl * 8 + (s ^ (pxl & 7))) * 8 + off) = pk;
    }
  }
  __syncthreads();
  // coalesced copy-out: 2048 chunks, 1 KB contiguous per wave-instr
#pragma unroll
  for (int it = 0; it < 4; ++it) {
    const int j = it * 512 + t;
    const int px = j >> 3, s = j & 7;
    const u16x8 v = xt[px * 8 + (s ^ (px & 7))];
    const int gpx = (ty0 + (px >> 4)) * WW + tx0 + (px & 15);
    *(u16x8*)(h + ((size_t)p * HWSZ + gpx) * CC + s * 8) = v;
  }
}

// ---------------------------------------------------------------- conv2
// grid (64 tiles 16x16, 8 batch), 512 thr, 2 blocks/CU. Loops both slots.
__global__ __launch_bounds__(512, 4) void conv2_kernel(const u16x8* __restrict__ h,
                                                       const u16x8* __restrict__ wp2,
                                                       const float* __restrict__ b2,
                                                       const int* __restrict__ eidx,
                                                       const float* __restrict__ gval,
                                                       float* __restrict__ out) {
  __shared__ u16x8 xt[XCH];
  __shared__ u16x8 wt[WHALF];
  const int t = threadIdx.x, lane = t & 63, w = t >> 6;
  const int tile = blockIdx.x, b = blockIdx.y;
  const int ty0 = (tile >> 3) * 16, tx0 = (tile & 7) * 16;

  f32x4 acc[2][4];
#pragma unroll
  for (int i = 0; i < 2; ++i)
#pragma unroll
    for (int j = 0; j < 4; ++j) acc[i][j] = (f32x4){0.f, 0.f, 0.f, 0.f};

#pragma unroll
  for (int slot = 0; slot < 2; ++slot) {
    const int p = 2 * b + slot;
    if (slot) __syncthreads();
    stage_xt(h + (size_t)p * HWSZ * 8, xt, ty0, tx0, t);
    stage_wt(wt, wp2 + (size_t)p * WCHUNKS, t);
    __syncthreads();
    half_body(xt, wt, 0, lane, w, acc);
    __syncthreads();
    stage_wt(wt, wp2 + (size_t)p * WCHUNKS + WHALF, t);
    __syncthreads();
    half_body(xt, wt, 1, lane, w, acc);
  }

  const int e0 = eidx[2 * b], e1 = eidx[2 * b + 1];
  const float g0 = gval[2 * b], g1 = gval[2 * b + 1];
  const int co_s = (lane >> 4) * 4;
  const int ln = lane & 15;
#pragma unroll
  for (int mf = 0; mf < 4; ++mf) {
    const float4 ba = *(const float4*)(b2 + e0 * CC + mf * 16 + co_s);
    const float4 bb = *(const float4*)(b2 + e1 * CC + mf * 16 + co_s);
    const float bx = g0 * ba.x + g1 * bb.x;
    const float by = g0 * ba.y + g1 * bb.y;
    const float bz = g0 * ba.z + g1 * bb.z;
    const float bw = g0 * ba.w + g1 * bb.w;
#pragma unroll
    for (int nfr = 0; nfr < 2; ++nfr) {
      const int row = 2 * w + nfr;
      const int gpx = (ty0 + row) * WW + tx0 + ln;
      f32x4 v = acc[nfr][mf];
      float* ob = out + (size_t)(b * CC + mf * 16 + co_s) * HWSZ + gpx;
      ob[0 * HWSZ] = v.x + bx;
      ob[1 * HWSZ] = v.y + by;
      ob[2 * HWSZ] = v.z + bz;
      ob[3 * HWSZ] = v.w + bw;
    }
  }
}

// ---------------------------------------------------------------- launch
extern "C" void kernel_launch(void* const* d_in, const int* in_sizes, int n_in,
                              void* d_out, int out_size, void* d_ws, size_t ws_size,
                              hipStream_t stream) {
  const float* x   = (const float*)d_in[0];
  const float* txt = (const float*)d_in[1];
  const float* Wx  = (const float*)d_in[2];
  const float* Wt  = (const float*)d_in[3];
  const float* w1  = (const float*)d_in[4];
  const float* b1  = (const float*)d_in[5];
  const float* w2  = (const float*)d_in[6];
  const float* b2  = (const float*)d_in[7];
  float* out = (float*)d_out;

  char* ws = (char*)d_ws;
  float* pooled = (float*)ws;                      // 2048 B
  int*   eidx   = (int*)(ws + 2048);               // 64 B
  float* gval   = (float*)(ws + 2112);             // 64 B
  unsigned short* wp1 = (unsigned short*)(ws + 4096);        // 1,179,648 B
  unsigned short* wp2 = (unsigned short*)(ws + 1183744);     // 1,179,648 B
  unsigned short* xT  = (unsigned short*)(ws + 2363392);     // 16,777,216 B
  unsigned short* h   = (unsigned short*)(ws + 19140608);    // 33,554,432 B

  hipMemsetAsync(pooled, 0, BB * CC * sizeof(float), stream);
  xtprep_kernel<<<dim3(64, 8), 256, 0, stream>>>(x, xT, pooled);
  gate_kernel<<<1, 256, 0, stream>>>(pooled, txt, Wx, Wt, eidx, gval,
                                     out + (out_size - 1));
  wprep_kernel<<<dim3(16, 2), 256, 0, stream>>>(w1, w2, eidx, gval, wp1, wp2);
  conv1_kernel<<<dim3(64, 16), 512, 0, stream>>>((const u16x8*)xT, (const u16x8*)wp1,
                                                 b1, eidx, (unsigned short*)h);
  conv2_kernel<<<dim3(64, 8), 512, 0, stream>>>((const u16x8*)h, (const u16x8*)wp2,
                                                b2, eidx, gval, out);
}

// Round 5
// 113.595 us; speedup vs baseline: 1.2049x; 1.1440x over previous
//
#include <hip/hip_runtime.h>
#include <hip/hip_bf16.h>
#include <math.h>

typedef __attribute__((ext_vector_type(8))) short      bf16x8;
typedef __attribute__((ext_vector_type(8))) unsigned short u16x8;
typedef __attribute__((ext_vector_type(4))) unsigned short u16x4;
typedef __attribute__((ext_vector_type(4))) float       f32x4;

#define BB 8
#define CC 64
#define HH 128
#define WW 128
#define EE 16
#define DTXT 512
#define HWSZ 16384
#define WCHUNKS 4608      // per pair: 2half * 9k * 4slot * 64co 16B chunks
#define WHALF 2304        // one 32-ci half
#define HLO 18            // 16x16 tile + halo
#define HPX2 324          // 18*18
#define XCH (HPX2 * 8)    // 2592 16B chunks

static __device__ __forceinline__ unsigned short f2bf(float f) {
  unsigned u = __float_as_uint(f);
  unsigned r = (u + 0x7FFFu + ((u >> 16) & 1u)) >> 16;  // RNE
  return (unsigned short)r;
}
static __device__ __forceinline__ float bf2f(unsigned short s) {
  return __uint_as_float(((unsigned)s) << 16);
}

// ---------------------------------------------------------------- xtprep (+pool partials)
// x[b][ci][px] fp32 -> xT[b][px][ci] bf16; pp[b][blk][ci] = per-block column sums.
__global__ __launch_bounds__(256) void xtprep_kernel(const float* __restrict__ x,
                                                     unsigned short* __restrict__ xT,
                                                     float* __restrict__ pp) {
  __shared__ unsigned short lt[256 * 70];
  __shared__ float red[256];
  const int b = blockIdx.y, p0 = blockIdx.x * 256;
  const int t = threadIdx.x;
  const float* xb = x + (size_t)b * CC * HWSZ + p0;
#pragma unroll 8
  for (int ci = 0; ci < CC; ++ci)
    lt[t * 70 + ci] = f2bf(xb[(size_t)ci * HWSZ + t]);
  __syncthreads();
  unsigned short* dstb = xT + ((size_t)b * HWSZ + p0) * CC;
#pragma unroll
  for (int it = 0; it < 8; ++it) {
    const int j = it * 256 + t;
    const int px = j >> 3, s = j & 7;
    u16x8 v;
#pragma unroll
    for (int i = 0; i < 8; ++i) v[i] = lt[px * 70 + s * 8 + i];
    *(u16x8*)(dstb + (size_t)j * 8) = v;
  }
  // pooled partial sums (no atomics; gate reduces)
  const int ci = t & 63, q = t >> 6;
  float s = 0.f;
#pragma unroll 16
  for (int px = q * 64; px < q * 64 + 64; ++px) s += bf2f(lt[px * 70 + ci]);
  red[t] = s;
  __syncthreads();
  if (t < 64)
    pp[((size_t)b * 64 + blockIdx.x) * 64 + t] =
        red[t] + red[t + 64] + red[t + 128] + red[t + 192];
}

// ---------------------------------------------------------------- gate
// reduce pooled partials, LDS-staged logit dots, top-2 softmax, aux loss.
__global__ __launch_bounds__(256) void gate_kernel(const float* __restrict__ pp,
                                                   const float* __restrict__ text,
                                                   const float* __restrict__ Wx,
                                                   const float* __restrict__ Wt,
                                                   int* __restrict__ eidx,
                                                   float* __restrict__ gval,
                                                   float* __restrict__ aux_out) {
  __shared__ float pl[BB][CC];        // 2 KB
  __shared__ float tx[BB * DTXT];     // 16 KB
  __shared__ float wtl[DTXT * EE];    // 32 KB
  __shared__ float logits[BB][EE];
  __shared__ float gates[BB][EE];
  __shared__ float imp[EE];
  const int t = threadIdx.x;

  // stage text + Wt via float4
#pragma unroll
  for (int i = 0; i < BB * DTXT / 4 / 256; ++i)
    ((float4*)tx)[i * 256 + t] = ((const float4*)text)[i * 256 + t];
#pragma unroll
  for (int i = 0; i < DTXT * EE / 4 / 256; ++i)
    ((float4*)wtl)[i * 256 + t] = ((const float4*)Wt)[i * 256 + t];

  // reduce pooled partials: 512 outputs, 2 per thread, coalesced over ci
#pragma unroll
  for (int jj = 0; jj < 2; ++jj) {
    const int j = jj * 256 + t;
    const int b = j >> 6, ci = j & 63;
    float s = 0.f;
#pragma unroll 8
    for (int blk = 0; blk < 64; ++blk) s += pp[((size_t)b * 64 + blk) * 64 + ci];
    pl[b][ci] = s * (1.f / (float)HWSZ);
  }
  __syncthreads();

  if (t < BB * EE) {
    const int b = t >> 4, e = t & 15;
    float s = 0.f;
#pragma unroll 8
    for (int c = 0; c < CC; ++c) s += pl[b][c] * Wx[c * EE + e];
#pragma unroll 8
    for (int d = 0; d < DTXT; ++d) s += tx[b * DTXT + d] * wtl[d * EE + e];
    logits[b][e] = s;
    gates[b][e] = 0.f;
  }
  __syncthreads();
  if (t < BB) {
    const int b = t;
    float v0 = -1e30f; int i0 = 0;
    for (int e = 0; e < EE; ++e) {
      float v = logits[b][e];
      if (v > v0) { v0 = v; i0 = e; }
    }
    float v1 = -1e30f; int i1 = 0;
    for (int e = 0; e < EE; ++e) {
      if (e == i0) continue;
      float v = logits[b][e];
      if (v > v1) { v1 = v; i1 = e; }
    }
    const float ex = expf(v1 - v0);
    const float g0 = 1.f / (1.f + ex);
    const float g1 = ex / (1.f + ex);
    gates[b][i0] = g0;
    gates[b][i1] = g1;
    eidx[2 * b] = i0;      gval[2 * b] = g0;
    eidx[2 * b + 1] = i1;  gval[2 * b + 1] = g1;
  }
  __syncthreads();
  if (t < EE) {
    float s = 0.f;
    for (int b = 0; b < BB; ++b) s += gates[b][t];
    imp[t] = s;
  }
  __syncthreads();
  if (t == 0) {
    float m = 0.f;
    for (int e = 0; e < EE; ++e) m += imp[e];
    m *= (1.f / EE);
    float v = 0.f;
    for (int e = 0; e < EE; ++e) { float d = imp[e] - m; v += d * d; }
    v *= (1.f / EE);
    aux_out[0] = v / (m * m + 1e-10f);
  }
}

// ---------------------------------------------------------------- wprep
// wp[pair][half2][k9][slot4][co64][8ci] bf16; gate folded into wp2.
__global__ __launch_bounds__(256) void wprep_kernel(const float* __restrict__ w1,
                                                    const float* __restrict__ w2,
                                                    const int* __restrict__ eidx,
                                                    const float* __restrict__ gval,
                                                    unsigned short* __restrict__ wp1,
                                                    unsigned short* __restrict__ wp2) {
  const int p = blockIdx.x;
  const int conv = blockIdx.y;
  const int e = eidx[p];
  const float g = conv ? gval[p] : 1.0f;
  const float* wsrc = (conv ? w2 : w1) + (size_t)e * CC * CC * 9;
  unsigned short* dst = (conv ? wp2 : wp1) + (size_t)p * WCHUNKS * 8;
  for (int c16 = threadIdx.x; c16 < WCHUNKS; c16 += 256) {
    const int co = c16 & 63;
    const int rest = c16 >> 6;
    const int s = rest & 3;
    const int ck = rest >> 2;
    const int k = ck % 9, half = ck / 9;
    const int ci0 = half * 32 + s * 8;
    u16x8 v;
#pragma unroll
    for (int i = 0; i < 8; ++i)
      v[i] = f2bf(g * wsrc[((size_t)co * CC + ci0 + i) * 9 + k]);
    *(u16x8*)(dst + (size_t)c16 * 8) = v;
  }
}

// ------------------------------------------------- conv core helpers
static __device__ __forceinline__ void stage_xt(const u16x8* __restrict__ src,
                                                u16x8* xt, int ty0, int tx0, int t) {
#pragma unroll
  for (int i = 0; i < 6; ++i) {
    const int idx = i * 512 + t;
    if (idx < XCH) {
      const int ph = idx >> 3, s = idx & 7;
      const int yy = ph / HLO, xx = ph - yy * HLO;
      const int gy = ty0 - 1 + yy, gx = tx0 - 1 + xx;
      u16x8 v = (u16x8){0, 0, 0, 0, 0, 0, 0, 0};
      if ((unsigned)gy < (unsigned)HH && (unsigned)gx < (unsigned)WW)
        v = src[(gy * WW + gx) * 8 + s];
      xt[ph * 8 + (s ^ (ph & 7))] = v;
    }
  }
}

static __device__ __forceinline__ void stage_wt(u16x8* wt,
                                                const u16x8* __restrict__ wsrc, int t) {
#pragma unroll
  for (int i = 0; i < 5; ++i) {
    const int idx = i * 512 + t;
    if (idx < WHALF) wt[idx] = wsrc[idx];
  }
}

static __device__ __forceinline__ void half_body(const u16x8* xt, const u16x8* wt,
                                                 int half, int lane, int w,
                                                 f32x4 acc[2][4]) {
  const int ks = lane >> 4, ln = lane & 15;
#pragma unroll
  for (int kk = 0; kk < 9; ++kk) {
    const int dy = kk / 3, dx = kk % 3;
    bf16x8 a[4];
#pragma unroll
    for (int mf = 0; mf < 4; ++mf)
      a[mf] = __builtin_bit_cast(bf16x8, wt[(kk * 4 + ks) * 64 + mf * 16 + ln]);
#pragma unroll
    for (int nfr = 0; nfr < 2; ++nfr) {
      const int row = 2 * w + nfr + dy;
      const int col = ln + dx;
      const int ph = row * HLO + col;
      const bf16x8 bfr = __builtin_bit_cast(bf16x8,
                xt[ph * 8 + ((half * 4 + ks) ^ (ph & 7))]);
#pragma unroll
      for (int mf = 0; mf < 4; ++mf)
        acc[nfr][mf] = __builtin_amdgcn_mfma_f32_16x16x32_bf16(a[mf], bfr,
                                                               acc[nfr][mf], 0, 0, 0);
    }
  }
}

// ---------------------------------------------------------------- conv1
// grid (64 tiles 16x16, 16 pairs), 512 thr, 2 blocks/CU.
__global__ __launch_bounds__(512, 4) void conv1_kernel(const u16x8* __restrict__ xT,
                                                       const u16x8* __restrict__ wp1,
                                                       const float* __restrict__ b1,
                                                       const int* __restrict__ eidx,
                                                       unsigned short* __restrict__ h) {
  __shared__ u16x8 xt[XCH];
  __shared__ u16x8 wt[WHALF];
  const int t = threadIdx.x, lane = t & 63, w = t >> 6;
  const int tile = blockIdx.x, p = blockIdx.y;
  const int b = p >> 1, e = eidx[p];
  const int ty0 = (tile >> 3) * 16, tx0 = (tile & 7) * 16;

  f32x4 acc[2][4];
#pragma unroll
  for (int i = 0; i < 2; ++i)
#pragma unroll
    for (int j = 0; j < 4; ++j) acc[i][j] = (f32x4){0.f, 0.f, 0.f, 0.f};

  stage_xt(xT + (size_t)b * HWSZ * 8, xt, ty0, tx0, t);
  stage_wt(wt, wp1 + (size_t)p * WCHUNKS, t);
  __syncthreads();
  half_body(xt, wt, 0, lane, w, acc);
  __syncthreads();
  stage_wt(wt, wp1 + (size_t)p * WCHUNKS + WHALF, t);
  __syncthreads();
  half_body(xt, wt, 1, lane, w, acc);
  __syncthreads();   // xt readers done; reuse xt for the store bounce

  // epilogue: bias + exact GELU -> swizzled LDS bounce
  unsigned short* lt = (unsigned short*)xt;
  const int co_s = (lane >> 4) * 4;
  const int ln = lane & 15;
#pragma unroll
  for (int mf = 0; mf < 4; ++mf) {
    const float4 bv = *(const float4*)(b1 + e * CC + mf * 16 + co_s);
    const int s = mf * 2 + (co_s >> 3);
    const int off = co_s & 7;
#pragma unroll
    for (int nfr = 0; nfr < 2; ++nfr) {
      const int pxl = (2 * w + nfr) * 16 + ln;
      f32x4 v = acc[nfr][mf];
      float r0 = v.x + bv.x, r1 = v.y + bv.y, r2 = v.z + bv.z, r3 = v.w + bv.w;
      r0 = 0.5f * r0 * (1.f + erff(r0 * 0.70710678118654752f));
      r1 = 0.5f * r1 * (1.f + erff(r1 * 0.70710678118654752f));
      r2 = 0.5f * r2 * (1.f + erff(r2 * 0.70710678118654752f));
      r3 = 0.5f * r3 * (1.f + erff(r3 * 0.70710678118654752f));
      u16x4 pk = {f2bf(r0), f2bf(r1), f2bf(r2), f2bf(r3)};
      *(u16x4*)(lt + (pxl * 8 + (s ^ (pxl & 7))) * 8 + off) = pk;
    }
  }
  __syncthreads();
  // coalesced copy-out: 2048 chunks, 1 KB contiguous per wave-instr
#pragma unroll
  for (int it = 0; it < 4; ++it) {
    const int j = it * 512 + t;
    const int px = j >> 3, s = j & 7;
    const u16x8 v = xt[px * 8 + (s ^ (px & 7))];
    const int gpx = (ty0 + (px >> 4)) * WW + tx0 + (px & 15);
    *(u16x8*)(h + ((size_t)p * HWSZ + gpx) * CC + s * 8) = v;
  }
}

// ---------------------------------------------------------------- conv2
// grid (64 tiles 16x16, 8 batch), 512 thr, 2 blocks/CU. Loops both slots.
__global__ __launch_bounds__(512, 4) void conv2_kernel(const u16x8* __restrict__ h,
                                                       const u16x8* __restrict__ wp2,
                                                       const float* __restrict__ b2,
                                                       const int* __restrict__ eidx,
                                                       const float* __restrict__ gval,
                                                       float* __restrict__ out) {
  __shared__ u16x8 xt[XCH];
  __shared__ u16x8 wt[WHALF];
  const int t = threadIdx.x, lane = t & 63, w = t >> 6;
  const int tile = blockIdx.x, b = blockIdx.y;
  const int ty0 = (tile >> 3) * 16, tx0 = (tile & 7) * 16;

  f32x4 acc[2][4];
#pragma unroll
  for (int i = 0; i < 2; ++i)
#pragma unroll
    for (int j = 0; j < 4; ++j) acc[i][j] = (f32x4){0.f, 0.f, 0.f, 0.f};

#pragma unroll
  for (int slot = 0; slot < 2; ++slot) {
    const int p = 2 * b + slot;
    if (slot) __syncthreads();
    stage_xt(h + (size_t)p * HWSZ * 8, xt, ty0, tx0, t);
    stage_wt(wt, wp2 + (size_t)p * WCHUNKS, t);
    __syncthreads();
    half_body(xt, wt, 0, lane, w, acc);
    __syncthreads();
    stage_wt(wt, wp2 + (size_t)p * WCHUNKS + WHALF, t);
    __syncthreads();
    half_body(xt, wt, 1, lane, w, acc);
  }

  const int e0 = eidx[2 * b], e1 = eidx[2 * b + 1];
  const float g0 = gval[2 * b], g1 = gval[2 * b + 1];
  const int co_s = (lane >> 4) * 4;
  const int ln = lane & 15;
#pragma unroll
  for (int mf = 0; mf < 4; ++mf) {
    const float4 ba = *(const float4*)(b2 + e0 * CC + mf * 16 + co_s);
    const float4 bb = *(const float4*)(b2 + e1 * CC + mf * 16 + co_s);
    const float bx = g0 * ba.x + g1 * bb.x;
    const float by = g0 * ba.y + g1 * bb.y;
    const float bz = g0 * ba.z + g1 * bb.z;
    const float bw = g0 * ba.w + g1 * bb.w;
#pragma unroll
    for (int nfr = 0; nfr < 2; ++nfr) {
      const int row = 2 * w + nfr;
      const int gpx = (ty0 + row) * WW + tx0 + ln;
      f32x4 v = acc[nfr][mf];
      float* ob = out + (size_t)(b * CC + mf * 16 + co_s) * HWSZ + gpx;
      ob[0 * HWSZ] = v.x + bx;
      ob[1 * HWSZ] = v.y + by;
      ob[2 * HWSZ] = v.z + bz;
      ob[3 * HWSZ] = v.w + bw;
    }
  }
}

// ---------------------------------------------------------------- launch
extern "C" void kernel_launch(void* const* d_in, const int* in_sizes, int n_in,
                              void* d_out, int out_size, void* d_ws, size_t ws_size,
                              hipStream_t stream) {
  const float* x   = (const float*)d_in[0];
  const float* txt = (const float*)d_in[1];
  const float* Wx  = (const float*)d_in[2];
  const float* Wt  = (const float*)d_in[3];
  const float* w1  = (const float*)d_in[4];
  const float* b1  = (const float*)d_in[5];
  const float* w2  = (const float*)d_in[6];
  const float* b2  = (const float*)d_in[7];
  float* out = (float*)d_out;

  char* ws = (char*)d_ws;
  float* pp   = (float*)ws;                                  // 131,072 B
  int*   eidx = (int*)(ws + 131072);                         // 64 B
  float* gval = (float*)(ws + 131136);                       // 64 B
  unsigned short* wp1 = (unsigned short*)(ws + 132096);      // 1,179,648 B
  unsigned short* wp2 = (unsigned short*)(ws + 1311744);     // 1,179,648 B
  unsigned short* xT  = (unsigned short*)(ws + 2491392);     // 16,777,216 B
  unsigned short* h   = (unsigned short*)(ws + 19268608);    // 33,554,432 B

  xtprep_kernel<<<dim3(64, 8), 256, 0, stream>>>(x, xT, pp);
  gate_kernel<<<1, 256, 0, stream>>>(pp, txt, Wx, Wt, eidx, gval,
                                     out + (out_size - 1));
  wprep_kernel<<<dim3(16, 2), 256, 0, stream>>>(w1, w2, eidx, gval, wp1, wp2);
  conv1_kernel<<<dim3(64, 16), 512, 0, stream>>>((const u16x8*)xT, (const u16x8*)wp1,
                                                 b1, eidx, (unsigned short*)h);
  conv2_kernel<<<dim3(64, 8), 512, 0, stream>>>((const u16x8*)h, (const u16x8*)wp2,
                                                b2, eidx, gval, out);
}